// Round 4
// baseline (325.286 us; speedup 1.0000x reference)
//
#include <hip/hip_runtime.h>
#include <cstdint>
#include <cstddef>

// ---------------------------------------------------------------------------
// Net_25950192402497: 2-layer MLP-message GNN + link-prediction head.
// Identity: segment_sum(concat(x_i,x_j,ef)@W + b) over dst
//   = deg*(h@Wi + b) + (gather-sum h[src])@Wj + (gather-sum ef)@We
// R16: gather = L2-capacity-bound (R13/R15 MLP work stopped paying; FETCH
// 106MB vs h=12.8MB, hit ~17%). Changes:
//  (a) feature-split gather: 2 launches x 64 cols -> h working set 6.4MB
//      per pass (fits-ish 4MB L2/XCD); separate launches so passes don't
//      interleave in cache.
//  (b) nontemporal loads (elist, ef) + stores (agg, efp, elist build) --
//      streams no longer evict h from L2.
//  (c) 8 lanes/node x uint4, 32 nodes/block, predicated batch-8 (same MLP).
// GEMMs kept at R15 form (gload16 staging, fused msg+pre).
// ---------------------------------------------------------------------------

typedef __attribute__((ext_vector_type(8))) short short8;
typedef __attribute__((ext_vector_type(4))) float float4v;
typedef __attribute__((ext_vector_type(4))) uint uint4v;
typedef __attribute__((ext_vector_type(2))) float float2v;

__device__ __forceinline__ ushort f2b(float f) {
    uint u = __float_as_uint(f);
    u = u + 0x7fff + ((u >> 16) & 1);          // round-to-nearest-even
    return (ushort)(u >> 16);
}
__device__ __forceinline__ float b2f(ushort h) {
    return __uint_as_float(((uint)h) << 16);
}
__device__ __forceinline__ uint pack2(float a, float b) {
    return (uint)f2b(a) | ((uint)f2b(b) << 16);
}

__device__ __forceinline__ void gload16(const void* gsrc, void* ldst) {
    __builtin_amdgcn_global_load_lds(
        (const __attribute__((address_space(1))) void*)gsrc,
        (__attribute__((address_space(3))) void*)ldst, 16, 0, 0);
}

#define F_MSG     1   // X = [hd | agg | efp] in k-space (Kp=320)
#define F_RELU    2
#define F_DEGBIAS 4
#define F_OUTB    8   // write bf16 output [row][128]
#define F_HEAD    32  // no row output; emit z[row] = {za0,za1,zb0,zb1}

// MFMA GEMM: act( X[r,0:Kp] @ W[Kp,128] + bias ).
// Wt: blocked+pre-swizzled bf16 [tile][n=128][64] (see prep).
// Block: 128 rows x 128 cols, 4 waves; wave w owns rows w*32..w*32+31.
// LDS xs/ws linear [128][64] halfwords; chunk swizzle ch^=(row&7) on 16B units.
__launch_bounds__(256, 3)
__global__ void gemm_mfma(const ushort* __restrict__ A, const ushort* __restrict__ B,
                          const ushort* __restrict__ EF,
                          const float* __restrict__ DEG, const ushort* __restrict__ Wt,
                          const float* __restrict__ bias, ushort* __restrict__ outB,
                          ushort* __restrict__ outD,
                          const float* __restrict__ lpW, float* __restrict__ z,
                          int M, int Kp, int flags)
{
    __shared__ ushort xs[128 * 64];   // 16 KB
    __shared__ ushort ws[128 * 64];   // 16 KB
    const int tid  = threadIdx.x;
    const int lane = tid & 63;
    const int wave = tid >> 6;
    const int row0 = blockIdx.x << 7;

    float4v acc[2][8];
#pragma unroll
    for (int m = 0; m < 2; ++m)
#pragma unroll
        for (int t = 0; t < 8; ++t) acc[m][t] = (float4v){0.f, 0.f, 0.f, 0.f};

    const int ar0   = (wave << 5) + (lane & 15);
    const int bcol  = lane & 15;
    const int cxor  = lane & 7;
    const int koffc = lane >> 4;
    const int sw16  = (((lane & 7) ^ (lane >> 3)) << 4);

    for (int kt = 0; kt < Kp; kt += 64) {
        const int tix = kt >> 6;
        __syncthreads();
        // ---- ws stage ----
#pragma unroll
        for (int i = 0; i < 4; ++i) {
            const int wsoff = (wave << 11) + (i << 9);
            gload16((const char*)Wt + (((size_t)((tix << 13) + wsoff)) << 1) + (lane << 4),
                    &ws[wsoff]);
        }
        // ---- xs stage ----
        {
            const char* srcB; size_t strideB; int toffB;
            if (flags & F_MSG) {
                if (tix < 2)      { srcB = (const char*)A;  strideB = 256; toffB = (tix & 1) << 7; }
                else if (tix < 4) { srcB = (const char*)B;  strideB = 256; toffB = (tix & 1) << 7; }
                else              { srcB = (const char*)EF; strideB = 128; toffB = 0; }
            } else {
                srcB = (const char*)A; strideB = 256; toffB = (tix & 1) << 7;
            }
            const int rb = wave << 5;
#pragma unroll
            for (int i = 0; i < 4; ++i) {
                const int gr = min(row0 + rb + (i << 3) + (lane >> 3), M - 1);
                gload16(srcB + (size_t)gr * strideB + toffB + sw16,
                        &xs[(rb + (i << 3)) << 6]);
            }
        }
        __syncthreads();
#pragma unroll
        for (int sc = 0; sc < 8; sc += 4) {
            const int ra = (sc + koffc) ^ cxor;
            const short8 a0 = *(const short8*)&xs[(ar0 << 6) + (ra << 3)];
            const short8 a1 = *(const short8*)&xs[((ar0 + 16) << 6) + (ra << 3)];
#pragma unroll
            for (int t = 0; t < 8; ++t) {
                const short8 bf = *(const short8*)&ws[(((t << 4) + bcol) << 6) + (ra << 3)];
                acc[0][t] = __builtin_amdgcn_mfma_f32_16x16x32_bf16(a0, bf, acc[0][t], 0, 0, 0);
                acc[1][t] = __builtin_amdgcn_mfma_f32_16x16x32_bf16(a1, bf, acc[1][t], 0, 0, 0);
            }
        }
    }

    // ---- epilogue: C/D layout col=lane&15, row=(lane>>4)*4+reg ----
    float bcv[8];
#pragma unroll
    for (int t = 0; t < 8; ++t) bcv[t] = bias[(t << 4) + bcol];

    if (flags & F_HEAD) {
        const float2* lw = (const float2*)lpW;
        float2 wa[8], wb[8];
#pragma unroll
        for (int t = 0; t < 8; ++t) {
            const int col = (t << 4) + bcol;
            wa[t] = lw[col];
            wb[t] = lw[128 + col];
        }
#pragma unroll
        for (int m = 0; m < 2; ++m) {
            const int rbase = row0 + (wave << 5) + (m << 4) + ((lane >> 4) << 2);
#pragma unroll
            for (int r = 0; r < 4; ++r) {
                const int row = rbase + r;
                const float d = (row < M) ? DEG[row] : 0.f;
                float za0 = 0.f, za1 = 0.f, zb0 = 0.f, zb1 = 0.f;
#pragma unroll
                for (int t = 0; t < 8; ++t) {
                    const float v = acc[m][t][r] + d * bcv[t];
                    za0 += v * wa[t].x; za1 += v * wa[t].y;
                    zb0 += v * wb[t].x; zb1 += v * wb[t].y;
                }
#pragma unroll
                for (int mk = 8; mk > 0; mk >>= 1) {
                    za0 += __shfl_xor(za0, mk);
                    za1 += __shfl_xor(za1, mk);
                    zb0 += __shfl_xor(zb0, mk);
                    zb1 += __shfl_xor(zb1, mk);
                }
                if (bcol == 0 && row < M)
                    *(float4*)&z[(size_t)row * 4] = make_float4(za0, za1, zb0, zb1);
            }
        }
    } else {
#pragma unroll
        for (int m = 0; m < 2; ++m) {
            const int rbase = row0 + (wave << 5) + (m << 4) + ((lane >> 4) << 2);
#pragma unroll
            for (int r = 0; r < 4; ++r) {
                const int row = rbase + r;
                if (row >= M) continue;
                const float d = DEG[row];
#pragma unroll
                for (int t = 0; t < 8; ++t) {
                    const int col = (t << 4) + bcol;
                    float v = acc[m][t][r];
                    v += (flags & F_DEGBIAS) ? d * bcv[t] : bcv[t];
                    if (flags & F_RELU) v = fmaxf(v, 0.f);
                    outB[((size_t)row << 7) + col] = f2b(v);
                    if (outD) outD[((size_t)row << 7) + col] = f2b(v * d);
                }
            }
        }
    }
}

// ---------------------------------------------------------------------------
// Fused conv1-msg + conv2-pre:
//   stage1: x1 = relu([HD|AGG|EFP] @ Wm + deg*bm)   (Kp=320, per-block tile)
//   stage2: h2 = relu(x1 @ Wp + bp); outH = h2, outHD = deg*h2
// x1 tile (128x128 bf16) lives only in LDS, stored in swizzled A-layout.
// ---------------------------------------------------------------------------
__launch_bounds__(256, 3)
__global__ void gemm_msg_pre(const ushort* __restrict__ HD, const ushort* __restrict__ AGG,
                             const ushort* __restrict__ EFP, const float* __restrict__ DEG,
                             const ushort* __restrict__ Wm, const float* __restrict__ bm,
                             const ushort* __restrict__ Wp, const float* __restrict__ bp,
                             ushort* __restrict__ outH, ushort* __restrict__ outHD, int M)
{
    __shared__ ushort smem[128 * 128 + 128 * 64];   // 48 KB: x2 tile + ws
    ushort* x2 = smem;             // [128][128] swizzled (stage1 xs uses first 16KB)
    ushort* ws = smem + 128 * 128; // [128][64]

    const int tid  = threadIdx.x;
    const int lane = tid & 63;
    const int wave = tid >> 6;
    const int row0 = blockIdx.x << 7;

    float4v acc[2][8];
#pragma unroll
    for (int m = 0; m < 2; ++m)
#pragma unroll
        for (int t = 0; t < 8; ++t) acc[m][t] = (float4v){0.f, 0.f, 0.f, 0.f};

    const int ar0   = (wave << 5) + (lane & 15);
    const int bcol  = lane & 15;
    const int cxor  = lane & 7;
    const int koffc = lane >> 4;
    const int sw16  = (((lane & 7) ^ (lane >> 3)) << 4);

    // ---- stage 1: Kp=320 over [HD | AGG | EFP] ----
    for (int kt = 0; kt < 320; kt += 64) {
        const int tix = kt >> 6;
        __syncthreads();
#pragma unroll
        for (int i = 0; i < 4; ++i) {
            const int wsoff = (wave << 11) + (i << 9);
            gload16((const char*)Wm + (((size_t)((tix << 13) + wsoff)) << 1) + (lane << 4),
                    &ws[wsoff]);
        }
        {
            const char* srcB; size_t strideB; int toffB;
            if (tix < 2)      { srcB = (const char*)HD;  strideB = 256; toffB = (tix & 1) << 7; }
            else if (tix < 4) { srcB = (const char*)AGG; strideB = 256; toffB = (tix & 1) << 7; }
            else              { srcB = (const char*)EFP; strideB = 128; toffB = 0; }
            const int rb = wave << 5;
#pragma unroll
            for (int i = 0; i < 4; ++i) {
                const int gr = min(row0 + rb + (i << 3) + (lane >> 3), M - 1);
                gload16(srcB + (size_t)gr * strideB + toffB + sw16,
                        &smem[(rb + (i << 3)) << 6]);
            }
        }
        __syncthreads();
#pragma unroll
        for (int sc = 0; sc < 8; sc += 4) {
            const int ra = (sc + koffc) ^ cxor;
            const short8 a0 = *(const short8*)&smem[(ar0 << 6) + (ra << 3)];
            const short8 a1 = *(const short8*)&smem[((ar0 + 16) << 6) + (ra << 3)];
#pragma unroll
            for (int t = 0; t < 8; ++t) {
                const short8 bf = *(const short8*)&ws[(((t << 4) + bcol) << 6) + (ra << 3)];
                acc[0][t] = __builtin_amdgcn_mfma_f32_16x16x32_bf16(a0, bf, acc[0][t], 0, 0, 0);
                acc[1][t] = __builtin_amdgcn_mfma_f32_16x16x32_bf16(a1, bf, acc[1][t], 0, 0, 0);
            }
        }
    }

    // ---- epilogue 1: x1 = relu(acc + deg*bm) -> x2 (LDS, swizzled) ----
    float bcv1[8];
#pragma unroll
    for (int t = 0; t < 8; ++t) bcv1[t] = bm[(t << 4) + bcol];

    __syncthreads();   // all stage-1 LDS reads complete before overwrite
#pragma unroll
    for (int m = 0; m < 2; ++m) {
        const int rl0 = (wave << 5) + (m << 4) + ((lane >> 4) << 2);
#pragma unroll
        for (int r = 0; r < 4; ++r) {
            const int rl  = rl0 + r;
            const int row = row0 + rl;
            const float d = (row < M) ? DEG[row] : 0.f;
#pragma unroll
            for (int t = 0; t < 8; ++t) {
                const int col = (t << 4) + bcol;
                const float v = fmaxf(acc[m][t][r] + d * bcv1[t], 0.f);
                const int ch = col >> 3;
                const int st = (ch & 8) | ((ch ^ rl) & 7);
                x2[(rl << 7) + (st << 3) + (col & 7)] = f2b(v);
            }
        }
    }

#pragma unroll
    for (int m = 0; m < 2; ++m)
#pragma unroll
        for (int t = 0; t < 8; ++t) acc[m][t] = (float4v){0.f, 0.f, 0.f, 0.f};

    // ---- stage 2: h2 = relu(x1 @ Wp + bp), K=128 ----
    for (int kt2 = 0; kt2 < 2; ++kt2) {
        __syncthreads();   // x2 writes visible (kt2=0) / ws reads done (kt2=1)
#pragma unroll
        for (int i = 0; i < 4; ++i) {
            const int wsoff = (wave << 11) + (i << 9);
            gload16((const char*)Wp + (((size_t)((kt2 << 13) + wsoff)) << 1) + (lane << 4),
                    &ws[wsoff]);
        }
        __syncthreads();
#pragma unroll
        for (int sc = 0; sc < 8; sc += 4) {
            const int ra = (sc + koffc) ^ cxor;
            const short8 a0 = *(const short8*)&x2[(ar0 << 7) + (kt2 << 6) + (ra << 3)];
            const short8 a1 = *(const short8*)&x2[((ar0 + 16) << 7) + (kt2 << 6) + (ra << 3)];
#pragma unroll
            for (int t = 0; t < 8; ++t) {
                const short8 bf = *(const short8*)&ws[(((t << 4) + bcol) << 6) + (ra << 3)];
                acc[0][t] = __builtin_amdgcn_mfma_f32_16x16x32_bf16(a0, bf, acc[0][t], 0, 0, 0);
                acc[1][t] = __builtin_amdgcn_mfma_f32_16x16x32_bf16(a1, bf, acc[1][t], 0, 0, 0);
            }
        }
    }

    // ---- epilogue 2: outH = relu(acc + bp), outHD = deg*outH ----
    float bcv2[8];
#pragma unroll
    for (int t = 0; t < 8; ++t) bcv2[t] = bp[(t << 4) + bcol];
#pragma unroll
    for (int m = 0; m < 2; ++m) {
        const int rbase = row0 + (wave << 5) + (m << 4) + ((lane >> 4) << 2);
#pragma unroll
        for (int r = 0; r < 4; ++r) {
            const int row = rbase + r;
            if (row >= M) continue;
            const float d = DEG[row];
#pragma unroll
            for (int t = 0; t < 8; ++t) {
                const int col = (t << 4) + bcol;
                const float v = fmaxf(acc[m][t][r] + bcv2[t], 0.f);
                outH[((size_t)row << 7) + col]  = f2b(v);
                outHD[((size_t)row << 7) + col] = f2b(v * d);
            }
        }
    }
}

// ---- prep: zero counts + efp, nf->bf16, blocked+pre-swizzled weights ----
__launch_bounds__(256)
__global__ void prep(const float* __restrict__ nf, ushort* __restrict__ nf_bf,
                     const float* __restrict__ c1pW, const float* __restrict__ c2pW,
                     const float* __restrict__ c1mW, const float* __restrict__ c2mW,
                     ushort* __restrict__ wtp1, ushort* __restrict__ wtp2,
                     ushort* __restrict__ wtm1, ushort* __restrict__ wtm2,
                     ushort* __restrict__ efp, int* __restrict__ counts, int N)
{
    const int gtid = blockIdx.x * 256 + threadIdx.x;
    const int gstr = gridDim.x * 256;
    for (int i = gtid; i < N; i += gstr) counts[i] = 0;
    // nf -> bf16 (8 floats -> one uint4 per iteration)
    for (int i = gtid; i < N * 16; i += gstr) {
        const float4 f0 = *(const float4*)&nf[(size_t)i * 8];
        const float4 f1 = *(const float4*)&nf[(size_t)i * 8 + 4];
        uint4 v;
        v.x = pack2(f0.x, f0.y); v.y = pack2(f0.z, f0.w);
        v.z = pack2(f1.x, f1.y); v.w = pack2(f1.z, f1.w);
        ((uint4*)nf_bf)[i] = v;
    }
    // zero efp: N rows x 64 halfwords = N*8 uint4
    for (int i = gtid; i < N * 8; i += gstr)
        ((uint4*)efp)[i] = make_uint4(0, 0, 0, 0);
    // pre weights: 2 tiles each
    for (int idx = gtid; idx < 2 * 128 * 64; idx += gstr) {
        const int s = idx & 63, n = (idx >> 6) & 127, t = idx >> 13;
        const int k = t * 64 + (((s >> 3) ^ (n & 7)) << 3) + (s & 7);
        wtp1[idx] = f2b(c1pW[(size_t)k * 128 + n]);
        wtp2[idx] = f2b(c2pW[(size_t)k * 128 + n]);
    }
    // msg weights: 5 tiles, Klim=272
    for (int idx = gtid; idx < 5 * 128 * 64; idx += gstr) {
        const int s = idx & 63, n = (idx >> 6) & 127, t = idx >> 13;
        const int k = t * 64 + (((s >> 3) ^ (n & 7)) << 3) + (s & 7);
        wtm1[idx] = (k < 272) ? f2b(c1mW[(size_t)k * 128 + n]) : (ushort)0;
        wtm2[idx] = (k < 272) ? f2b(c2mW[(size_t)k * 128 + n]) : (ushort)0;
    }
}

__launch_bounds__(256)
__global__ void hist_kernel(const int* __restrict__ ei, int* __restrict__ counts, int E)
{
    const int e = blockIdx.x * 256 + threadIdx.x;
    if (e < E) atomicAdd(&counts[ei[E + e]], 1);
}

__launch_bounds__(256)
__global__ void scan_phase1(const int* __restrict__ counts, int* __restrict__ rowstart,
                            int* __restrict__ blocksums, int N)
{
    __shared__ int sdata[256];
    const int t = threadIdx.x;
    const int i = blockIdx.x * 256 + t;
    const int v = (i < N) ? counts[i] : 0;
    sdata[t] = v;
    __syncthreads();
    for (int off = 1; off < 256; off <<= 1) {
        const int add = (t >= off) ? sdata[t - off] : 0;
        __syncthreads();
        sdata[t] += add;
        __syncthreads();
    }
    if (i < N) rowstart[i] = sdata[t] - v;
    if (t == 255) blocksums[blockIdx.x] = sdata[255];
}

// merged scan phases 2+3: block vb sums blocksums[0..vb) itself (~196 blocks)
__launch_bounds__(256)
__global__ void scan_phase23(const int* __restrict__ counts, const int* __restrict__ bs,
                             int* __restrict__ rowstart, int* __restrict__ cursor,
                             float* __restrict__ degf, int N, int E)
{
    __shared__ int sdata[256];
    const int t = threadIdx.x;
    const int vb = blockIdx.x;
    int part = 0;
    for (int j = t; j < vb; j += 256) part += bs[j];
    sdata[t] = part;
    __syncthreads();
    for (int s = 128; s > 0; s >>= 1) {
        if (t < s) sdata[t] += sdata[t + s];
        __syncthreads();
    }
    const int off = sdata[0];
    const int i = vb * 256 + t;
    if (i < N) {
        const int rs = rowstart[i] + off;
        rowstart[i] = rs;
        cursor[i]   = rs;
        degf[i]     = (float)counts[i];
    }
    if (vb == 0 && t == 0) rowstart[N] = E;
}

__launch_bounds__(256)
__global__ void build_elist(const int* __restrict__ ei, int* __restrict__ cursor,
                            int2* __restrict__ elist, int E)
{
    const int e = blockIdx.x * 256 + threadIdx.x;
    if (e >= E) return;
    const int d = ei[E + e];
    const int pos = atomicAdd(&cursor[d], 1);
    // nontemporal: elist is consumed later from other XCDs; don't pollute L2
    const unsigned long long rec = (unsigned long long)(uint)ei[e]
                                 | ((unsigned long long)(uint)e << 32);
    __builtin_nontemporal_store(rec, (unsigned long long*)&elist[pos]);
}

// gather (R16): one launch per 64-col half (pass). 8 lanes/node x uint4
// (128B row-half), 32 nodes/block, predicated batch-8. elist/ef loads and
// agg/efp stores are nontemporal; only h occupies L2 (working set 6.4MB).
__launch_bounds__(256)
__global__ void gather(const int2* __restrict__ elist, const int* __restrict__ rowstart,
                       const ushort* __restrict__ h, ushort* __restrict__ agg,
                       const float* __restrict__ ef, ushort* __restrict__ aggef,
                       int N, int doEf, int pass)
{
    const int tid = threadIdx.x;
    const int grp = tid >> 3;          // 0..31 (node group within block)
    const int l   = tid & 7;           // lane within group
    const int co  = pass << 6;         // halfword column offset (0 or 64)
    const int nvb = (N + 31) / 32;     // 32 nodes per block
    for (int vb = blockIdx.x; vb < nvb; vb += gridDim.x) {
        const int node = vb * 32 + grp;
        if (node >= N) continue;
        const int beg = rowstart[node];
        const int end = rowstart[node + 1];
        float a0 = 0.f, a1 = 0.f, a2 = 0.f, a3 = 0.f;
        float a4 = 0.f, a5 = 0.f, a6 = 0.f, a7 = 0.f;
        float e0 = 0.f, e1 = 0.f;
        for (int k = beg; k < end; k += 8) {
            const int cnt = min(8, end - k);
            const unsigned long long epll = __builtin_nontemporal_load(
                (const unsigned long long*)&elist[k + min(l, cnt - 1)]);
            const int epx = (int)(uint)epll;
            const int epy = (int)(uint)(epll >> 32);
            uint4 v[8];
            float2v efv[8];
#pragma unroll
            for (int jj = 0; jj < 8; ++jj) {
                const int idx = min(jj, cnt - 1);
                const int s = __shfl(epx, idx, 8);
                v[jj] = *(const uint4*)&h[((size_t)s << 7) + co + (l << 3)];
                if (doEf) {
                    const int y = __shfl(epy, idx, 8);
                    efv[jj] = __builtin_nontemporal_load(
                        (const float2v*)&ef[((size_t)y << 4) + (l << 1)]);
                }
            }
#pragma unroll
            for (int jj = 0; jj < 8; ++jj) {
                if (jj >= cnt) {
                    v[jj] = make_uint4(0, 0, 0, 0);
                    if (doEf) { efv[jj].x = 0.f; efv[jj].y = 0.f; }
                }
                a0 += b2f((ushort)(v[jj].x & 0xffff));
                a1 += b2f((ushort)(v[jj].x >> 16));
                a2 += b2f((ushort)(v[jj].y & 0xffff));
                a3 += b2f((ushort)(v[jj].y >> 16));
                a4 += b2f((ushort)(v[jj].z & 0xffff));
                a5 += b2f((ushort)(v[jj].z >> 16));
                a6 += b2f((ushort)(v[jj].w & 0xffff));
                a7 += b2f((ushort)(v[jj].w >> 16));
                if (doEf) { e0 += efv[jj].x; e1 += efv[jj].y; }
            }
        }
        uint4v o;
        o.x = pack2(a0, a1);
        o.y = pack2(a2, a3);
        o.z = pack2(a4, a5);
        o.w = pack2(a6, a7);
        __builtin_nontemporal_store(o, (uint4v*)&agg[((size_t)node << 7) + co + (l << 3)]);
        if (doEf)
            __builtin_nontemporal_store(pack2(e0, e1),
                                        &((uint*)&aggef[(size_t)node << 6])[l]);
    }
}

// head: out[q] = z[a].topdot + z[b].botdot + lpb  (z = {za0,za1,zb0,zb1})
__launch_bounds__(256)
__global__ void head_kernel(const float4* __restrict__ z, const int* __restrict__ eli,
                            const float* __restrict__ lpb, float* __restrict__ out, int Q)
{
    const int q = blockIdx.x * 256 + threadIdx.x;
    if (q >= Q) return;
    const int a = eli[q];
    const int b = eli[Q + q];
    const float4 za = z[a];
    const float4 zb = z[b];
    float2 o = make_float2(za.x + zb.z + lpb[0], za.y + zb.w + lpb[1]);
    *(float2*)&out[(size_t)q * 2] = o;
}

extern "C" void kernel_launch(void* const* d_in, const int* in_sizes, int n_in,
                              void* d_out, int out_size, void* d_ws, size_t ws_size,
                              hipStream_t stream)
{
    const float* nf   = (const float*)d_in[0];
    const int*   ei   = (const int*)d_in[1];
    const float* ef   = (const float*)d_in[2];
    const int*   eli  = (const int*)d_in[3];
    const float* c1pW = (const float*)d_in[4];
    const float* c1pb = (const float*)d_in[5];
    const float* c1mW = (const float*)d_in[6];
    const float* c1mb = (const float*)d_in[7];
    const float* c2pW = (const float*)d_in[8];
    const float* c2pb = (const float*)d_in[9];
    const float* c2mW = (const float*)d_in[10];
    const float* c2mb = (const float*)d_in[11];
    const float* lpW  = (const float*)d_in[12];
    const float* lpb  = (const float*)d_in[13];
    float* out = (float*)d_out;

    const int N = in_sizes[0] / 128;
    const int E = in_sizes[1] / 2;
    const int Q = in_sizes[3] / 2;

    // ---- workspace layout ----
    float* DEG = (float*)d_ws;                 // N
    float* z   = DEG + N;                      // N*4 fp32 (head projections)
    int* counts    = (int*)(z + (size_t)N * 4);// N
    int* rowstart  = counts + N;               // N+1
    int* cursor    = rowstart + N + 1;         // N
    int* blocksums = cursor + N;               // 1024 pad
    uintptr_t ep8 = (uintptr_t)(blocksums + 1024);
    ep8 = (ep8 + 7) & ~(uintptr_t)7;
    int2* elist = (int2*)ep8;                  // E int2 (src, edge id)
    uintptr_t up = (uintptr_t)(elist + E);
    up = (up + 15) & ~(uintptr_t)15;
    ushort* nf_bf  = (ushort*)up;              // N*128
    ushort* h_bf   = nf_bf  + (size_t)N * 128; // N*128
    ushort* agg_bf = h_bf   + (size_t)N * 128; // N*128
    ushort* hd_bf  = agg_bf + (size_t)N * 128; // N*128 (deg-scaled h)
    ushort* efp    = hd_bf  + (size_t)N * 128; // N*64 (zero-padded ef sums)
    ushort* wtp1   = efp    + (size_t)N * 64;  // 2*128*64
    ushort* wtm1   = wtp1 + 2 * 128 * 64;      // 5*128*64
    ushort* wtp2   = wtm1 + 5 * 128 * 64;      // 2*128*64
    ushort* wtm2   = wtp2 + 2 * 128 * 64;      // 5*128*64

    const int gemmGrid = (N + 127) / 128;
    const int eGrid    = (E + 255) / 256;
    const int nGrid    = (N + 255) / 256;
    const int gGrid    = (N + 31) / 32;
    const int headGrid = (Q + 255) / 256;

    // ---- prep + CSR build ----
    prep<<<nGrid, 256, 0, stream>>>(nf, nf_bf, c1pW, c2pW, c1mW, c2mW,
                                    wtp1, wtp2, wtm1, wtm2, efp, counts, N);
    hist_kernel<<<eGrid, 256, 0, stream>>>(ei, counts, E);
    scan_phase1<<<nGrid, 256, 0, stream>>>(counts, rowstart, blocksums, N);
    scan_phase23<<<nGrid, 256, 0, stream>>>(counts, blocksums, rowstart, cursor, DEG, N, E);
    build_elist<<<eGrid, 256, 0, stream>>>(ei, cursor, elist, E);

    // ---- conv1 ----
    gemm_mfma<<<gemmGrid, 256, 0, stream>>>(nf_bf, nullptr, nullptr, DEG, wtp1,
                                            c1pb, h_bf, hd_bf, nullptr, nullptr, N, 128,
                                            F_RELU | F_OUTB);
    gather<<<gGrid, 256, 0, stream>>>(elist, rowstart, h_bf, agg_bf, ef, efp, N, 1, 0);
    gather<<<gGrid, 256, 0, stream>>>(elist, rowstart, h_bf, agg_bf, nullptr, nullptr, N, 0, 1);

    // ---- conv1-msg + conv2-pre (fused) ----
    gemm_msg_pre<<<gemmGrid, 256, 0, stream>>>(hd_bf, agg_bf, efp, DEG, wtm1, c1mb,
                                               wtp2, c2pb, h_bf, hd_bf, N);

    // ---- conv2 ----
    gather<<<gGrid, 256, 0, stream>>>(elist, rowstart, h_bf, agg_bf, nullptr, nullptr, N, 0, 0);
    gather<<<gGrid, 256, 0, stream>>>(elist, rowstart, h_bf, agg_bf, nullptr, nullptr, N, 0, 1);
    gemm_mfma<<<gemmGrid, 256, 0, stream>>>(hd_bf, agg_bf, efp, DEG, wtm2,
                                            c2mb, nullptr, nullptr, lpW, z, N, 320,
                                            F_MSG | F_DEGBIAS | F_HEAD);

    // ---- head ----
    head_kernel<<<headGrid, 256, 0, stream>>>((const float4*)z, eli, lpb, out, Q);
}

// Round 5
// 288.768 us; speedup vs baseline: 1.1265x; 1.1265x over previous
//
#include <hip/hip_runtime.h>
#include <cstdint>
#include <cstddef>

// ---------------------------------------------------------------------------
// Net_25950192402497: 2-layer MLP-message GNN + link-prediction head.
// Identity: segment_sum(concat(x_i,x_j,ef)@W + b) over dst
//   = deg*(h@Wi + b) + (gather-sum h[src])@Wj + (gather-sum ef)@We
// R17:
//  (a) gather REVERTED to R15 form (feature-split was request-rate-bound:
//      2x passes = 2x time, +39us). 16 lanes/node, uint4, predicated batch-8.
//  (b) GEMMs: BM=64 tiles (grid 391 -> 782 blocks). R16 counters showed
//      gemm_msg_pre at Occ 14.5% / MfmaUtil 4.7% -- grid-starved at 391
//      blocks on 256 CUs. Smaller tiles trade MFMA density (irrelevant at
//      4.7%) for 2x block parallelism + lower LDS (24/32KB) + lower VGPR.
// ---------------------------------------------------------------------------

typedef __attribute__((ext_vector_type(8))) short short8;
typedef __attribute__((ext_vector_type(4))) float float4v;

__device__ __forceinline__ ushort f2b(float f) {
    uint u = __float_as_uint(f);
    u = u + 0x7fff + ((u >> 16) & 1);          // round-to-nearest-even
    return (ushort)(u >> 16);
}
__device__ __forceinline__ float b2f(ushort h) {
    return __uint_as_float(((uint)h) << 16);
}
__device__ __forceinline__ uint pack2(float a, float b) {
    return (uint)f2b(a) | ((uint)f2b(b) << 16);
}

__device__ __forceinline__ void gload16(const void* gsrc, void* ldst) {
    __builtin_amdgcn_global_load_lds(
        (const __attribute__((address_space(1))) void*)gsrc,
        (__attribute__((address_space(3))) void*)ldst, 16, 0, 0);
}

#define F_MSG     1   // X = [hd | agg | efp] in k-space (Kp=320)
#define F_RELU    2
#define F_DEGBIAS 4
#define F_OUTB    8   // write bf16 output [row][128]
#define F_HEAD    32  // no row output; emit z[row] = {za0,za1,zb0,zb1}

// MFMA GEMM: act( X[r,0:Kp] @ W[Kp,128] + bias ).
// Wt: blocked+pre-swizzled bf16 [tile][n=128][64] (see prep).
// Block: 64 rows x 128 cols, 4 waves; wave w owns rows w*16..w*16+15,
// all 128 cols as 8 col-tiles. acc = 8 x float4.
// LDS xs [64][64], ws [128][64]; chunk swizzle ch^=(row&7) on 16B units.
__launch_bounds__(256, 4)
__global__ void gemm_mfma(const ushort* __restrict__ A, const ushort* __restrict__ B,
                          const ushort* __restrict__ EF,
                          const float* __restrict__ DEG, const ushort* __restrict__ Wt,
                          const float* __restrict__ bias, ushort* __restrict__ outB,
                          ushort* __restrict__ outD,
                          const float* __restrict__ lpW, float* __restrict__ z,
                          int M, int Kp, int flags)
{
    __shared__ ushort xs[64 * 64];    // 8 KB
    __shared__ ushort ws[128 * 64];   // 16 KB
    const int tid  = threadIdx.x;
    const int lane = tid & 63;
    const int wave = tid >> 6;
    const int row0 = blockIdx.x << 6;

    float4v acc[8];
#pragma unroll
    for (int t = 0; t < 8; ++t) acc[t] = (float4v){0.f, 0.f, 0.f, 0.f};

    const int ar0   = (wave << 4) + (lane & 15);
    const int bcol  = lane & 15;
    const int cxor  = lane & 7;
    const int koffc = lane >> 4;
    const int sw16  = (((lane & 7) ^ (lane >> 3)) << 4);

    for (int kt = 0; kt < Kp; kt += 64) {
        const int tix = kt >> 6;
        __syncthreads();
        // ---- ws stage ----
#pragma unroll
        for (int i = 0; i < 4; ++i) {
            const int wsoff = (wave << 11) + (i << 9);
            gload16((const char*)Wt + (((size_t)((tix << 13) + wsoff)) << 1) + (lane << 4),
                    &ws[wsoff]);
        }
        // ---- xs stage ----
        {
            const char* srcB; size_t strideB; int toffB;
            if (flags & F_MSG) {
                if (tix < 2)      { srcB = (const char*)A;  strideB = 256; toffB = (tix & 1) << 7; }
                else if (tix < 4) { srcB = (const char*)B;  strideB = 256; toffB = (tix & 1) << 7; }
                else              { srcB = (const char*)EF; strideB = 128; toffB = 0; }
            } else {
                srcB = (const char*)A; strideB = 256; toffB = (tix & 1) << 7;
            }
            const int rb = wave << 4;
#pragma unroll
            for (int i = 0; i < 2; ++i) {
                const int gr = min(row0 + rb + (i << 3) + (lane >> 3), M - 1);
                gload16(srcB + (size_t)gr * strideB + toffB + sw16,
                        &xs[(rb + (i << 3)) << 6]);
            }
        }
        __syncthreads();
#pragma unroll
        for (int sc = 0; sc < 8; sc += 4) {
            const int ra = (sc + koffc) ^ cxor;
            const short8 a0 = *(const short8*)&xs[(ar0 << 6) + (ra << 3)];
#pragma unroll
            for (int t = 0; t < 8; ++t) {
                const short8 bf = *(const short8*)&ws[(((t << 4) + bcol) << 6) + (ra << 3)];
                acc[t] = __builtin_amdgcn_mfma_f32_16x16x32_bf16(a0, bf, acc[t], 0, 0, 0);
            }
        }
    }

    // ---- epilogue: C/D layout col=lane&15, row=(lane>>4)*4+reg ----
    float bcv[8];
#pragma unroll
    for (int t = 0; t < 8; ++t) bcv[t] = bias[(t << 4) + bcol];

    if (flags & F_HEAD) {
        const float2* lw = (const float2*)lpW;
        float2 wa[8], wb[8];
#pragma unroll
        for (int t = 0; t < 8; ++t) {
            const int col = (t << 4) + bcol;
            wa[t] = lw[col];
            wb[t] = lw[128 + col];
        }
        const int rbase = row0 + (wave << 4) + ((lane >> 4) << 2);
#pragma unroll
        for (int r = 0; r < 4; ++r) {
            const int row = rbase + r;
            const float d = (row < M) ? DEG[row] : 0.f;
            float za0 = 0.f, za1 = 0.f, zb0 = 0.f, zb1 = 0.f;
#pragma unroll
            for (int t = 0; t < 8; ++t) {
                const float v = acc[t][r] + d * bcv[t];
                za0 += v * wa[t].x; za1 += v * wa[t].y;
                zb0 += v * wb[t].x; zb1 += v * wb[t].y;
            }
#pragma unroll
            for (int mk = 8; mk > 0; mk >>= 1) {
                za0 += __shfl_xor(za0, mk);
                za1 += __shfl_xor(za1, mk);
                zb0 += __shfl_xor(zb0, mk);
                zb1 += __shfl_xor(zb1, mk);
            }
            if (bcol == 0 && row < M)
                *(float4*)&z[(size_t)row * 4] = make_float4(za0, za1, zb0, zb1);
        }
    } else {
        const int rbase = row0 + (wave << 4) + ((lane >> 4) << 2);
#pragma unroll
        for (int r = 0; r < 4; ++r) {
            const int row = rbase + r;
            if (row >= M) continue;
            const float d = DEG[row];
#pragma unroll
            for (int t = 0; t < 8; ++t) {
                const int col = (t << 4) + bcol;
                float v = acc[t][r];
                v += (flags & F_DEGBIAS) ? d * bcv[t] : bcv[t];
                if (flags & F_RELU) v = fmaxf(v, 0.f);
                outB[((size_t)row << 7) + col] = f2b(v);
                if (outD) outD[((size_t)row << 7) + col] = f2b(v * d);
            }
        }
    }
}

// ---------------------------------------------------------------------------
// Fused conv1-msg + conv2-pre (BM=64):
//   stage1: x1 = relu([HD|AGG|EFP] @ Wm + deg*bm)   (Kp=320, per-block tile)
//   stage2: h2 = relu(x1 @ Wp + bp); outH = h2, outHD = deg*h2
// x1 tile (64x128 bf16) lives only in LDS, swizzled A-layout:
//   idx = rl*128 + ((ch&8)|((ch^rl)&7))*8 + (col&7), ch = col>>3.
// stage1 xs region reuses x2's first 8KB.
// ---------------------------------------------------------------------------
__launch_bounds__(256, 4)
__global__ void gemm_msg_pre(const ushort* __restrict__ HD, const ushort* __restrict__ AGG,
                             const ushort* __restrict__ EFP, const float* __restrict__ DEG,
                             const ushort* __restrict__ Wm, const float* __restrict__ bm,
                             const ushort* __restrict__ Wp, const float* __restrict__ bp,
                             ushort* __restrict__ outH, ushort* __restrict__ outHD, int M)
{
    __shared__ ushort smem[64 * 128 + 128 * 64];   // 32 KB: x2 tile + ws
    ushort* x2 = smem;             // [64][128] swizzled (stage1 xs = first 8KB)
    ushort* ws = smem + 64 * 128;  // [128][64]

    const int tid  = threadIdx.x;
    const int lane = tid & 63;
    const int wave = tid >> 6;
    const int row0 = blockIdx.x << 6;

    float4v acc[8];
#pragma unroll
    for (int t = 0; t < 8; ++t) acc[t] = (float4v){0.f, 0.f, 0.f, 0.f};

    const int ar0   = (wave << 4) + (lane & 15);
    const int bcol  = lane & 15;
    const int cxor  = lane & 7;
    const int koffc = lane >> 4;
    const int sw16  = (((lane & 7) ^ (lane >> 3)) << 4);

    // ---- stage 1: Kp=320 over [HD | AGG | EFP] ----
    for (int kt = 0; kt < 320; kt += 64) {
        const int tix = kt >> 6;
        __syncthreads();
#pragma unroll
        for (int i = 0; i < 4; ++i) {
            const int wsoff = (wave << 11) + (i << 9);
            gload16((const char*)Wm + (((size_t)((tix << 13) + wsoff)) << 1) + (lane << 4),
                    &ws[wsoff]);
        }
        {
            const char* srcB; size_t strideB; int toffB;
            if (tix < 2)      { srcB = (const char*)HD;  strideB = 256; toffB = (tix & 1) << 7; }
            else if (tix < 4) { srcB = (const char*)AGG; strideB = 256; toffB = (tix & 1) << 7; }
            else              { srcB = (const char*)EFP; strideB = 128; toffB = 0; }
            const int rb = wave << 4;
#pragma unroll
            for (int i = 0; i < 2; ++i) {
                const int gr = min(row0 + rb + (i << 3) + (lane >> 3), M - 1);
                gload16(srcB + (size_t)gr * strideB + toffB + sw16,
                        &smem[(rb + (i << 3)) << 6]);
            }
        }
        __syncthreads();
#pragma unroll
        for (int sc = 0; sc < 8; sc += 4) {
            const int ra = (sc + koffc) ^ cxor;
            const short8 a0 = *(const short8*)&smem[(ar0 << 6) + (ra << 3)];
#pragma unroll
            for (int t = 0; t < 8; ++t) {
                const short8 bf = *(const short8*)&ws[(((t << 4) + bcol) << 6) + (ra << 3)];
                acc[t] = __builtin_amdgcn_mfma_f32_16x16x32_bf16(a0, bf, acc[t], 0, 0, 0);
            }
        }
    }

    // ---- epilogue 1: x1 = relu(acc + deg*bm) -> x2 (LDS, swizzled) ----
    float bcv1[8];
#pragma unroll
    for (int t = 0; t < 8; ++t) bcv1[t] = bm[(t << 4) + bcol];

    __syncthreads();   // all stage-1 LDS reads complete before overwrite
    {
        const int rl0 = (wave << 4) + ((lane >> 4) << 2);
#pragma unroll
        for (int r = 0; r < 4; ++r) {
            const int rl  = rl0 + r;
            const int row = row0 + rl;
            const float d = (row < M) ? DEG[row] : 0.f;
#pragma unroll
            for (int t = 0; t < 8; ++t) {
                const int col = (t << 4) + bcol;
                const float v = fmaxf(acc[t][r] + d * bcv1[t], 0.f);
                const int ch = col >> 3;
                const int st = (ch & 8) | ((ch ^ rl) & 7);
                x2[(rl << 7) + (st << 3) + (col & 7)] = f2b(v);
            }
        }
    }

#pragma unroll
    for (int t = 0; t < 8; ++t) acc[t] = (float4v){0.f, 0.f, 0.f, 0.f};

    // ---- stage 2: h2 = relu(x1 @ Wp + bp), K=128 ----
    for (int kt2 = 0; kt2 < 2; ++kt2) {
        __syncthreads();   // x2 writes visible (kt2=0) / ws reads done (kt2=1)
#pragma unroll
        for (int i = 0; i < 4; ++i) {
            const int wsoff = (wave << 11) + (i << 9);
            gload16((const char*)Wp + (((size_t)((kt2 << 13) + wsoff)) << 1) + (lane << 4),
                    &ws[wsoff]);
        }
        __syncthreads();
#pragma unroll
        for (int sc = 0; sc < 8; sc += 4) {
            const int ra = (sc + koffc) ^ cxor;
            const short8 a0 = *(const short8*)&x2[(ar0 << 7) + (kt2 << 6) + (ra << 3)];
#pragma unroll
            for (int t = 0; t < 8; ++t) {
                const short8 bf = *(const short8*)&ws[(((t << 4) + bcol) << 6) + (ra << 3)];
                acc[t] = __builtin_amdgcn_mfma_f32_16x16x32_bf16(a0, bf, acc[t], 0, 0, 0);
            }
        }
    }

    // ---- epilogue 2: outH = relu(acc + bp), outHD = deg*outH ----
    float bcv2[8];
#pragma unroll
    for (int t = 0; t < 8; ++t) bcv2[t] = bp[(t << 4) + bcol];
    {
        const int rbase = row0 + (wave << 4) + ((lane >> 4) << 2);
#pragma unroll
        for (int r = 0; r < 4; ++r) {
            const int row = rbase + r;
            if (row >= M) continue;
            const float d = DEG[row];
#pragma unroll
            for (int t = 0; t < 8; ++t) {
                const int col = (t << 4) + bcol;
                const float v = fmaxf(acc[t][r] + bcv2[t], 0.f);
                outH[((size_t)row << 7) + col]  = f2b(v);
                outHD[((size_t)row << 7) + col] = f2b(v * d);
            }
        }
    }
}

// ---- prep: zero counts + efp, nf->bf16, blocked+pre-swizzled weights ----
__launch_bounds__(256)
__global__ void prep(const float* __restrict__ nf, ushort* __restrict__ nf_bf,
                     const float* __restrict__ c1pW, const float* __restrict__ c2pW,
                     const float* __restrict__ c1mW, const float* __restrict__ c2mW,
                     ushort* __restrict__ wtp1, ushort* __restrict__ wtp2,
                     ushort* __restrict__ wtm1, ushort* __restrict__ wtm2,
                     ushort* __restrict__ efp, int* __restrict__ counts, int N)
{
    const int gtid = blockIdx.x * 256 + threadIdx.x;
    const int gstr = gridDim.x * 256;
    for (int i = gtid; i < N; i += gstr) counts[i] = 0;
    // nf -> bf16 (8 floats -> one uint4 per iteration)
    for (int i = gtid; i < N * 16; i += gstr) {
        const float4 f0 = *(const float4*)&nf[(size_t)i * 8];
        const float4 f1 = *(const float4*)&nf[(size_t)i * 8 + 4];
        uint4 v;
        v.x = pack2(f0.x, f0.y); v.y = pack2(f0.z, f0.w);
        v.z = pack2(f1.x, f1.y); v.w = pack2(f1.z, f1.w);
        ((uint4*)nf_bf)[i] = v;
    }
    // zero efp: N rows x 64 halfwords = N*8 uint4
    for (int i = gtid; i < N * 8; i += gstr)
        ((uint4*)efp)[i] = make_uint4(0, 0, 0, 0);
    // pre weights: 2 tiles each
    for (int idx = gtid; idx < 2 * 128 * 64; idx += gstr) {
        const int s = idx & 63, n = (idx >> 6) & 127, t = idx >> 13;
        const int k = t * 64 + (((s >> 3) ^ (n & 7)) << 3) + (s & 7);
        wtp1[idx] = f2b(c1pW[(size_t)k * 128 + n]);
        wtp2[idx] = f2b(c2pW[(size_t)k * 128 + n]);
    }
    // msg weights: 5 tiles, Klim=272
    for (int idx = gtid; idx < 5 * 128 * 64; idx += gstr) {
        const int s = idx & 63, n = (idx >> 6) & 127, t = idx >> 13;
        const int k = t * 64 + (((s >> 3) ^ (n & 7)) << 3) + (s & 7);
        wtm1[idx] = (k < 272) ? f2b(c1mW[(size_t)k * 128 + n]) : (ushort)0;
        wtm2[idx] = (k < 272) ? f2b(c2mW[(size_t)k * 128 + n]) : (ushort)0;
    }
}

__launch_bounds__(256)
__global__ void hist_kernel(const int* __restrict__ ei, int* __restrict__ counts, int E)
{
    const int e = blockIdx.x * 256 + threadIdx.x;
    if (e < E) atomicAdd(&counts[ei[E + e]], 1);
}

__launch_bounds__(256)
__global__ void scan_phase1(const int* __restrict__ counts, int* __restrict__ rowstart,
                            int* __restrict__ blocksums, int N)
{
    __shared__ int sdata[256];
    const int t = threadIdx.x;
    const int i = blockIdx.x * 256 + t;
    const int v = (i < N) ? counts[i] : 0;
    sdata[t] = v;
    __syncthreads();
    for (int off = 1; off < 256; off <<= 1) {
        const int add = (t >= off) ? sdata[t - off] : 0;
        __syncthreads();
        sdata[t] += add;
        __syncthreads();
    }
    if (i < N) rowstart[i] = sdata[t] - v;
    if (t == 255) blocksums[blockIdx.x] = sdata[255];
}

// merged scan phases 2+3: block vb sums blocksums[0..vb) itself (~196 blocks)
__launch_bounds__(256)
__global__ void scan_phase23(const int* __restrict__ counts, const int* __restrict__ bs,
                             int* __restrict__ rowstart, int* __restrict__ cursor,
                             float* __restrict__ degf, int N, int E)
{
    __shared__ int sdata[256];
    const int t = threadIdx.x;
    const int vb = blockIdx.x;
    int part = 0;
    for (int j = t; j < vb; j += 256) part += bs[j];
    sdata[t] = part;
    __syncthreads();
    for (int s = 128; s > 0; s >>= 1) {
        if (t < s) sdata[t] += sdata[t + s];
        __syncthreads();
    }
    const int off = sdata[0];
    const int i = vb * 256 + t;
    if (i < N) {
        const int rs = rowstart[i] + off;
        rowstart[i] = rs;
        cursor[i]   = rs;
        degf[i]     = (float)counts[i];
    }
    if (vb == 0 && t == 0) rowstart[N] = E;
}

__launch_bounds__(256)
__global__ void build_elist(const int* __restrict__ ei, int* __restrict__ cursor,
                            int2* __restrict__ elist, int E)
{
    const int e = blockIdx.x * 256 + threadIdx.x;
    if (e >= E) return;
    const int d = ei[E + e];
    const int pos = atomicAdd(&cursor[d], 1);
    elist[pos] = make_int2(ei[e], e);
}

// gather (R15 form): 16 lanes/node (4 nodes/wave), uint4/lane/edge, fully
// predicated batches of 8 (clamped src index, zeroed contribution). elist
// read once per 16-edge chunk + __shfl broadcast. ef fused (writes efp).
__launch_bounds__(256)
__global__ void gather(const int2* __restrict__ elist, const int* __restrict__ rowstart,
                       const ushort* __restrict__ h, ushort* __restrict__ agg,
                       const float* __restrict__ ef, ushort* __restrict__ aggef,
                       int N, int doEf)
{
    const int tid = threadIdx.x;
    const int grp = tid >> 4;          // 0..15 (node group within block)
    const int l   = tid & 15;          // lane within group
    const int nvb = (N + 15) / 16;     // 16 nodes per block
    for (int vb = blockIdx.x; vb < nvb; vb += gridDim.x) {
        const int node = vb * 16 + grp;
        if (node >= N) continue;
        const int beg = rowstart[node];
        const int end = rowstart[node + 1];
        float a0 = 0.f, a1 = 0.f, a2 = 0.f, a3 = 0.f;
        float a4 = 0.f, a5 = 0.f, a6 = 0.f, a7 = 0.f;
        float efacc = 0.f;
        for (int k = beg; k < end; k += 16) {
            const int cnt = min(16, end - k);
            const int2 ep = elist[k + min(l, cnt - 1)];   // 16 records, 1 vec load
            for (int j = 0; j < cnt; j += 8) {
                uint4 v[8];
                float efv[8];
#pragma unroll
                for (int jj = 0; jj < 8; ++jj) {
                    const int idx = min(j + jj, cnt - 1);
                    const int s = __shfl(ep.x, idx, 16);
                    v[jj] = *(const uint4*)&h[((size_t)s << 7) + (l << 3)];
                    if (doEf) {
                        const int y = __shfl(ep.y, idx, 16);
                        efv[jj] = ef[((size_t)y << 4) + l];
                    }
                }
#pragma unroll
                for (int jj = 0; jj < 8; ++jj) {
                    if (j + jj >= cnt) {
                        v[jj] = make_uint4(0, 0, 0, 0);
                        efv[jj] = 0.f;
                    }
                    a0 += b2f((ushort)(v[jj].x & 0xffff));
                    a1 += b2f((ushort)(v[jj].x >> 16));
                    a2 += b2f((ushort)(v[jj].y & 0xffff));
                    a3 += b2f((ushort)(v[jj].y >> 16));
                    a4 += b2f((ushort)(v[jj].z & 0xffff));
                    a5 += b2f((ushort)(v[jj].z >> 16));
                    a6 += b2f((ushort)(v[jj].w & 0xffff));
                    a7 += b2f((ushort)(v[jj].w >> 16));
                    if (doEf) efacc += efv[jj];
                }
            }
        }
        uint4 o;
        o.x = pack2(a0, a1);
        o.y = pack2(a2, a3);
        o.z = pack2(a4, a5);
        o.w = pack2(a6, a7);
        *(uint4*)&agg[((size_t)node << 7) + (l << 3)] = o;
        if (doEf) aggef[((size_t)node << 6) + l] = f2b(efacc);
    }
}

// head: out[q] = z[a].topdot + z[b].botdot + lpb  (z = {za0,za1,zb0,zb1})
__launch_bounds__(256)
__global__ void head_kernel(const float4* __restrict__ z, const int* __restrict__ eli,
                            const float* __restrict__ lpb, float* __restrict__ out, int Q)
{
    const int q = blockIdx.x * 256 + threadIdx.x;
    if (q >= Q) return;
    const int a = eli[q];
    const int b = eli[Q + q];
    const float4 za = z[a];
    const float4 zb = z[b];
    float2 o = make_float2(za.x + zb.z + lpb[0], za.y + zb.w + lpb[1]);
    *(float2*)&out[(size_t)q * 2] = o;
}

extern "C" void kernel_launch(void* const* d_in, const int* in_sizes, int n_in,
                              void* d_out, int out_size, void* d_ws, size_t ws_size,
                              hipStream_t stream)
{
    const float* nf   = (const float*)d_in[0];
    const int*   ei   = (const int*)d_in[1];
    const float* ef   = (const float*)d_in[2];
    const int*   eli  = (const int*)d_in[3];
    const float* c1pW = (const float*)d_in[4];
    const float* c1pb = (const float*)d_in[5];
    const float* c1mW = (const float*)d_in[6];
    const float* c1mb = (const float*)d_in[7];
    const float* c2pW = (const float*)d_in[8];
    const float* c2pb = (const float*)d_in[9];
    const float* c2mW = (const float*)d_in[10];
    const float* c2mb = (const float*)d_in[11];
    const float* lpW  = (const float*)d_in[12];
    const float* lpb  = (const float*)d_in[13];
    float* out = (float*)d_out;

    const int N = in_sizes[0] / 128;
    const int E = in_sizes[1] / 2;
    const int Q = in_sizes[3] / 2;

    // ---- workspace layout ----
    float* DEG = (float*)d_ws;                 // N
    float* z   = DEG + N;                      // N*4 fp32 (head projections)
    int* counts    = (int*)(z + (size_t)N * 4);// N
    int* rowstart  = counts + N;               // N+1
    int* cursor    = rowstart + N + 1;         // N
    int* blocksums = cursor + N;               // 1024 pad
    uintptr_t ep8 = (uintptr_t)(blocksums + 1024);
    ep8 = (ep8 + 7) & ~(uintptr_t)7;
    int2* elist = (int2*)ep8;                  // E int2 (src, edge id)
    uintptr_t up = (uintptr_t)(elist + E);
    up = (up + 15) & ~(uintptr_t)15;
    ushort* nf_bf  = (ushort*)up;              // N*128
    ushort* h_bf   = nf_bf  + (size_t)N * 128; // N*128
    ushort* agg_bf = h_bf   + (size_t)N * 128; // N*128
    ushort* hd_bf  = agg_bf + (size_t)N * 128; // N*128 (deg-scaled h)
    ushort* efp    = hd_bf  + (size_t)N * 128; // N*64 (zero-padded ef sums)
    ushort* wtp1   = efp    + (size_t)N * 64;  // 2*128*64
    ushort* wtm1   = wtp1 + 2 * 128 * 64;      // 5*128*64
    ushort* wtp2   = wtm1 + 5 * 128 * 64;      // 2*128*64
    ushort* wtm2   = wtp2 + 2 * 128 * 64;      // 5*128*64

    const int gemmGrid = (N + 63) / 64;
    const int eGrid    = (E + 255) / 256;
    const int nGrid    = (N + 255) / 256;
    const int gGrid    = (N + 15) / 16;
    const int headGrid = (Q + 255) / 256;

    // ---- prep + CSR build ----
    prep<<<nGrid, 256, 0, stream>>>(nf, nf_bf, c1pW, c2pW, c1mW, c2mW,
                                    wtp1, wtp2, wtm1, wtm2, efp, counts, N);
    hist_kernel<<<eGrid, 256, 0, stream>>>(ei, counts, E);
    scan_phase1<<<nGrid, 256, 0, stream>>>(counts, rowstart, blocksums, N);
    scan_phase23<<<nGrid, 256, 0, stream>>>(counts, blocksums, rowstart, cursor, DEG, N, E);
    build_elist<<<eGrid, 256, 0, stream>>>(ei, cursor, elist, E);

    // ---- conv1 ----
    gemm_mfma<<<gemmGrid, 256, 0, stream>>>(nf_bf, nullptr, nullptr, DEG, wtp1,
                                            c1pb, h_bf, hd_bf, nullptr, nullptr, N, 128,
                                            F_RELU | F_OUTB);
    gather<<<gGrid, 256, 0, stream>>>(elist, rowstart, h_bf, agg_bf, ef, efp, N, 1);

    // ---- conv1-msg + conv2-pre (fused) ----
    gemm_msg_pre<<<gemmGrid, 256, 0, stream>>>(hd_bf, agg_bf, efp, DEG, wtm1, c1mb,
                                               wtp2, c2pb, h_bf, hd_bf, N);

    // ---- conv2 ----
    gather<<<gGrid, 256, 0, stream>>>(elist, rowstart, h_bf, agg_bf, nullptr, nullptr, N, 0);
    gemm_mfma<<<gemmGrid, 256, 0, stream>>>(hd_bf, agg_bf, efp, DEG, wtm2,
                                            c2mb, nullptr, nullptr, lpW, z, N, 320,
                                            F_MSG | F_DEGBIAS | F_HEAD);

    // ---- head ----
    head_kernel<<<headGrid, 256, 0, stream>>>((const float4*)z, eli, lpb, out, Q);
}

// Round 9
// 282.168 us; speedup vs baseline: 1.1528x; 1.0234x over previous
//
#include <hip/hip_runtime.h>
#include <cstdint>
#include <cstddef>

// ---------------------------------------------------------------------------
// Net_25950192402497: 2-layer MLP-message GNN + link-prediction head.
// Identity: segment_sum(concat(x_i,x_j,ef)@W + b) over dst
//   = deg*(h@Wi + b) + (gather-sum h[src])@Wj + (gather-sum ef)@We
// R21: counted-vmcnt pipeline REVERTED (R19 corrupt, R20 intermittent —
// m152-class race; 2 strikes -> back to the verified R17 __syncthreads
// K-loop). New: dual-accumulator MSG GEMM. deg*h@Wi == deg*(h@Wi), so MSG
// GEMMs accumulate h-tiles (k<128) into acc0 and agg/efp tiles into acc1;
// epilogue combines v = deg*(acc0+bm) + acc1. hd_bf is GONE (saves 2x
// 12.8MB writes + epilogue stores); msg_pre reads/writes h_bf in place
// (block touches only its own rows; __restrict__ dropped on aliased args).
// Gather/CSR/prep/head = R15/R17 verified form.
// ---------------------------------------------------------------------------

typedef __attribute__((ext_vector_type(8))) short short8;
typedef __attribute__((ext_vector_type(4))) float float4v;

__device__ __forceinline__ ushort f2b(float f) {
    uint u = __float_as_uint(f);
    u = u + 0x7fff + ((u >> 16) & 1);          // round-to-nearest-even
    return (ushort)(u >> 16);
}
__device__ __forceinline__ float b2f(ushort h) {
    return __uint_as_float(((uint)h) << 16);
}
__device__ __forceinline__ uint pack2(float a, float b) {
    return (uint)f2b(a) | ((uint)f2b(b) << 16);
}

__device__ __forceinline__ void gload16(const void* gsrc, void* ldst) {
    __builtin_amdgcn_global_load_lds(
        (const __attribute__((address_space(1))) void*)gsrc,
        (__attribute__((address_space(3))) void*)ldst, 16, 0, 0);
}

#define F_MSG     1   // X = [h | agg | efp] in k-space (Kp=320), dual-acc
#define F_RELU    2
#define F_OUTB    8   // write bf16 output [row][128]
#define F_HEAD    32  // no row output; emit z[row] = {za0,za1,zb0,zb1}

// MFMA GEMM: act( X[r,0:Kp] @ W[Kp,128] + bias ).
// Wt: blocked+pre-swizzled bf16 [tile][n=128][64] (see prep).
// Block: 64 rows x 128 cols, 4 waves; wave w owns rows w*16..w*16+15.
// LDS xs [64][64], ws [128][64]; chunk swizzle ch^=(row&7) on 16B units.
// F_MSG: tiles 0-1 (h) -> acc0, tiles 2-4 (agg/efp) -> acc1;
//        out = deg*(acc0+bias) + acc1  (uniform branch, static acc index).
__launch_bounds__(256, 4)
__global__ void gemm_mfma(const ushort* A, const ushort* __restrict__ B,
                          const ushort* __restrict__ EF,
                          const float* __restrict__ DEG, const ushort* __restrict__ Wt,
                          const float* __restrict__ bias, ushort* outB,
                          const float* __restrict__ lpW, float* __restrict__ z,
                          int M, int Kp, int flags)
{
    __shared__ ushort xs[64 * 64];    // 8 KB
    __shared__ ushort ws[128 * 64];   // 16 KB
    const int tid  = threadIdx.x;
    const int lane = tid & 63;
    const int wave = tid >> 6;
    const int row0 = blockIdx.x << 6;

    float4v acc0[8], acc1[8];
#pragma unroll
    for (int t = 0; t < 8; ++t) {
        acc0[t] = (float4v){0.f, 0.f, 0.f, 0.f};
        acc1[t] = (float4v){0.f, 0.f, 0.f, 0.f};
    }

    const int ar0   = (wave << 4) + (lane & 15);
    const int bcol  = lane & 15;
    const int cxor  = lane & 7;
    const int koffc = lane >> 4;
    const int sw16  = (((lane & 7) ^ (lane >> 3)) << 4);

    for (int kt = 0; kt < Kp; kt += 64) {
        const int tix = kt >> 6;
        __syncthreads();
        // ---- ws stage ----
#pragma unroll
        for (int i = 0; i < 4; ++i) {
            const int wsoff = (wave << 11) + (i << 9);
            gload16((const char*)Wt + (((size_t)((tix << 13) + wsoff)) << 1) + (lane << 4),
                    &ws[wsoff]);
        }
        // ---- xs stage ----
        {
            const char* srcB; size_t strideB; int toffB;
            if (flags & F_MSG) {
                if (tix < 2)      { srcB = (const char*)A;  strideB = 256; toffB = (tix & 1) << 7; }
                else if (tix < 4) { srcB = (const char*)B;  strideB = 256; toffB = (tix & 1) << 7; }
                else              { srcB = (const char*)EF; strideB = 128; toffB = 0; }
            } else {
                srcB = (const char*)A; strideB = 256; toffB = (tix & 1) << 7;
            }
            const int rb = wave << 4;
#pragma unroll
            for (int i = 0; i < 2; ++i) {
                const int gr = min(row0 + rb + (i << 3) + (lane >> 3), M - 1);
                gload16(srcB + (size_t)gr * strideB + toffB + sw16,
                        &xs[(rb + (i << 3)) << 6]);
            }
        }
        __syncthreads();
        const bool toB = (flags & F_MSG) && (tix >= 2);   // wave-uniform
#pragma unroll
        for (int sc = 0; sc < 8; sc += 4) {
            const int ra = (sc + koffc) ^ cxor;
            const short8 a0 = *(const short8*)&xs[(ar0 << 6) + (ra << 3)];
            if (toB) {
#pragma unroll
                for (int t = 0; t < 8; ++t) {
                    const short8 bf = *(const short8*)&ws[(((t << 4) + bcol) << 6) + (ra << 3)];
                    acc1[t] = __builtin_amdgcn_mfma_f32_16x16x32_bf16(a0, bf, acc1[t], 0, 0, 0);
                }
            } else {
#pragma unroll
                for (int t = 0; t < 8; ++t) {
                    const short8 bf = *(const short8*)&ws[(((t << 4) + bcol) << 6) + (ra << 3)];
                    acc0[t] = __builtin_amdgcn_mfma_f32_16x16x32_bf16(a0, bf, acc0[t], 0, 0, 0);
                }
            }
        }
    }

    // ---- epilogue: C/D layout col=lane&15, row=(lane>>4)*4+reg ----
    float bcv[8];
#pragma unroll
    for (int t = 0; t < 8; ++t) bcv[t] = bias[(t << 4) + bcol];

    if (flags & F_HEAD) {
        const float2* lw = (const float2*)lpW;
        float2 wa[8], wb[8];
#pragma unroll
        for (int t = 0; t < 8; ++t) {
            const int col = (t << 4) + bcol;
            wa[t] = lw[col];
            wb[t] = lw[128 + col];
        }
        const int rbase = row0 + (wave << 4) + ((lane >> 4) << 2);
#pragma unroll
        for (int r = 0; r < 4; ++r) {
            const int row = rbase + r;
            const float d = (row < M) ? DEG[row] : 0.f;
            float za0 = 0.f, za1 = 0.f, zb0 = 0.f, zb1 = 0.f;
#pragma unroll
            for (int t = 0; t < 8; ++t) {
                const float v = d * (acc0[t][r] + bcv[t]) + acc1[t][r];
                za0 += v * wa[t].x; za1 += v * wa[t].y;
                zb0 += v * wb[t].x; zb1 += v * wb[t].y;
            }
#pragma unroll
            for (int mk = 8; mk > 0; mk >>= 1) {
                za0 += __shfl_xor(za0, mk);
                za1 += __shfl_xor(za1, mk);
                zb0 += __shfl_xor(zb0, mk);
                zb1 += __shfl_xor(zb1, mk);
            }
            if (bcol == 0 && row < M)
                *(float4*)&z[(size_t)row * 4] = make_float4(za0, za1, zb0, zb1);
        }
    } else {
        const int rbase = row0 + (wave << 4) + ((lane >> 4) << 2);
#pragma unroll
        for (int r = 0; r < 4; ++r) {
            const int row = rbase + r;
            if (row >= M) continue;
            const float d = DEG[row];
#pragma unroll
            for (int t = 0; t < 8; ++t) {
                const int col = (t << 4) + bcol;
                float v;
                if (flags & F_MSG) v = d * (acc0[t][r] + bcv[t]) + acc1[t][r];
                else               v = acc0[t][r] + bcv[t];
                if (flags & F_RELU) v = fmaxf(v, 0.f);
                outB[((size_t)row << 7) + col] = f2b(v);
            }
        }
    }
}

// ---------------------------------------------------------------------------
// Fused conv1-msg + conv2-pre (BM=64, dual-acc stage1):
//   stage1: x1 = relu( deg*(h@Wm[0:128] + bm) + [agg|efp]@Wm[128:320] )
//   stage2: h2 = relu(x1 @ Wp + bp); outH = h2
// x1 tile (64x128 bf16) lives only in LDS, swizzled A-layout.
// H and outH may alias (in-place h update: block reads only its own rows,
// writes them strictly after all reads) -> no __restrict__ on H/outH.
// ---------------------------------------------------------------------------
__launch_bounds__(256, 4)
__global__ void gemm_msg_pre(const ushort* H, const ushort* __restrict__ AGG,
                             const ushort* __restrict__ EFP, const float* __restrict__ DEG,
                             const ushort* __restrict__ Wm, const float* __restrict__ bm,
                             const ushort* __restrict__ Wp, const float* __restrict__ bp,
                             ushort* outH, int M)
{
    __shared__ ushort smem[64 * 128 + 128 * 64];   // 32 KB: x2 tile + ws
    ushort* x2 = smem;             // [64][128] swizzled (stage1 xs = first 8KB)
    ushort* ws = smem + 64 * 128;  // [128][64]

    const int tid  = threadIdx.x;
    const int lane = tid & 63;
    const int wave = tid >> 6;
    const int row0 = blockIdx.x << 6;

    float4v acc0[8], acc1[8];
#pragma unroll
    for (int t = 0; t < 8; ++t) {
        acc0[t] = (float4v){0.f, 0.f, 0.f, 0.f};
        acc1[t] = (float4v){0.f, 0.f, 0.f, 0.f};
    }

    const int ar0   = (wave << 4) + (lane & 15);
    const int bcol  = lane & 15;
    const int cxor  = lane & 7;
    const int koffc = lane >> 4;
    const int sw16  = (((lane & 7) ^ (lane >> 3)) << 4);

    // ---- stage 1: Kp=320 over [H | AGG | EFP], dual accumulate ----
    for (int kt = 0; kt < 320; kt += 64) {
        const int tix = kt >> 6;
        __syncthreads();
#pragma unroll
        for (int i = 0; i < 4; ++i) {
            const int wsoff = (wave << 11) + (i << 9);
            gload16((const char*)Wm + (((size_t)((tix << 13) + wsoff)) << 1) + (lane << 4),
                    &ws[wsoff]);
        }
        {
            const char* srcB; size_t strideB; int toffB;
            if (tix < 2)      { srcB = (const char*)H;   strideB = 256; toffB = (tix & 1) << 7; }
            else if (tix < 4) { srcB = (const char*)AGG; strideB = 256; toffB = (tix & 1) << 7; }
            else              { srcB = (const char*)EFP; strideB = 128; toffB = 0; }
            const int rb = wave << 4;
#pragma unroll
            for (int i = 0; i < 2; ++i) {
                const int gr = min(row0 + rb + (i << 3) + (lane >> 3), M - 1);
                gload16(srcB + (size_t)gr * strideB + toffB + sw16,
                        &smem[(rb + (i << 3)) << 6]);
            }
        }
        __syncthreads();
        const bool toB = (tix >= 2);   // wave-uniform
#pragma unroll
        for (int sc = 0; sc < 8; sc += 4) {
            const int ra = (sc + koffc) ^ cxor;
            const short8 a0 = *(const short8*)&smem[(ar0 << 6) + (ra << 3)];
            if (toB) {
#pragma unroll
                for (int t = 0; t < 8; ++t) {
                    const short8 bf = *(const short8*)&ws[(((t << 4) + bcol) << 6) + (ra << 3)];
                    acc1[t] = __builtin_amdgcn_mfma_f32_16x16x32_bf16(a0, bf, acc1[t], 0, 0, 0);
                }
            } else {
#pragma unroll
                for (int t = 0; t < 8; ++t) {
                    const short8 bf = *(const short8*)&ws[(((t << 4) + bcol) << 6) + (ra << 3)];
                    acc0[t] = __builtin_amdgcn_mfma_f32_16x16x32_bf16(a0, bf, acc0[t], 0, 0, 0);
                }
            }
        }
    }

    // ---- epilogue 1: x1 = relu(deg*(acc0+bm) + acc1) -> x2 (LDS, swizzled) ----
    float bcv1[8];
#pragma unroll
    for (int t = 0; t < 8; ++t) bcv1[t] = bm[(t << 4) + bcol];

    __syncthreads();   // all stage-1 LDS reads complete before overwrite
    {
        const int rl0 = (wave << 4) + ((lane >> 4) << 2);
#pragma unroll
        for (int r = 0; r < 4; ++r) {
            const int rl  = rl0 + r;
            const int row = row0 + rl;
            const float d = (row < M) ? DEG[row] : 0.f;
#pragma unroll
            for (int t = 0; t < 8; ++t) {
                const int col = (t << 4) + bcol;
                const float v = fmaxf(d * (acc0[t][r] + bcv1[t]) + acc1[t][r], 0.f);
                const int ch = col >> 3;
                const int st = (ch & 8) | ((ch ^ rl) & 7);
                x2[(rl << 7) + (st << 3) + (col & 7)] = f2b(v);
            }
        }
    }

#pragma unroll
    for (int t = 0; t < 8; ++t) acc0[t] = (float4v){0.f, 0.f, 0.f, 0.f};

    // ---- stage 2: h2 = relu(x1 @ Wp + bp), K=128 (LDS-resident x1) ----
    for (int kt2 = 0; kt2 < 2; ++kt2) {
        __syncthreads();   // x2 writes visible (kt2=0) / ws reads done (kt2=1)
#pragma unroll
        for (int i = 0; i < 4; ++i) {
            const int wsoff = (wave << 11) + (i << 9);
            gload16((const char*)Wp + (((size_t)((kt2 << 13) + wsoff)) << 1) + (lane << 4),
                    &ws[wsoff]);
        }
        __syncthreads();
#pragma unroll
        for (int sc = 0; sc < 8; sc += 4) {
            const int ra = (sc + koffc) ^ cxor;
            const short8 a0 = *(const short8*)&x2[(ar0 << 7) + (kt2 << 6) + (ra << 3)];
#pragma unroll
            for (int t = 0; t < 8; ++t) {
                const short8 bf = *(const short8*)&ws[(((t << 4) + bcol) << 6) + (ra << 3)];
                acc0[t] = __builtin_amdgcn_mfma_f32_16x16x32_bf16(a0, bf, acc0[t], 0, 0, 0);
            }
        }
    }

    // ---- epilogue 2: outH = relu(acc0 + bp) ----
    float bcv2[8];
#pragma unroll
    for (int t = 0; t < 8; ++t) bcv2[t] = bp[(t << 4) + bcol];
    {
        const int rbase = row0 + (wave << 4) + ((lane >> 4) << 2);
#pragma unroll
        for (int r = 0; r < 4; ++r) {
            const int row = rbase + r;
            if (row >= M) continue;
#pragma unroll
            for (int t = 0; t < 8; ++t) {
                const int col = (t << 4) + bcol;
                const float v = fmaxf(acc0[t][r] + bcv2[t], 0.f);
                outH[((size_t)row << 7) + col] = f2b(v);
            }
        }
    }
}

// ---- prep: zero counts + efp, nf->bf16, blocked+pre-swizzled weights ----
__launch_bounds__(256)
__global__ void prep(const float* __restrict__ nf, ushort* __restrict__ nf_bf,
                     const float* __restrict__ c1pW, const float* __restrict__ c2pW,
                     const float* __restrict__ c1mW, const float* __restrict__ c2mW,
                     ushort* __restrict__ wtp1, ushort* __restrict__ wtp2,
                     ushort* __restrict__ wtm1, ushort* __restrict__ wtm2,
                     ushort* __restrict__ efp, int* __restrict__ counts, int N)
{
    const int gtid = blockIdx.x * 256 + threadIdx.x;
    const int gstr = gridDim.x * 256;
    for (int i = gtid; i < N; i += gstr) counts[i] = 0;
    // nf -> bf16 (8 floats -> one uint4 per iteration)
    for (int i = gtid; i < N * 16; i += gstr) {
        const float4 f0 = *(const float4*)&nf[(size_t)i * 8];
        const float4 f1 = *(const float4*)&nf[(size_t)i * 8 + 4];
        uint4 v;
        v.x = pack2(f0.x, f0.y); v.y = pack2(f0.z, f0.w);
        v.z = pack2(f1.x, f1.y); v.w = pack2(f1.z, f1.w);
        ((uint4*)nf_bf)[i] = v;
    }
    // zero efp: N rows x 64 halfwords = N*8 uint4
    for (int i = gtid; i < N * 8; i += gstr)
        ((uint4*)efp)[i] = make_uint4(0, 0, 0, 0);
    // pre weights: 2 tiles each
    for (int idx = gtid; idx < 2 * 128 * 64; idx += gstr) {
        const int s = idx & 63, n = (idx >> 6) & 127, t = idx >> 13;
        const int k = t * 64 + (((s >> 3) ^ (n & 7)) << 3) + (s & 7);
        wtp1[idx] = f2b(c1pW[(size_t)k * 128 + n]);
        wtp2[idx] = f2b(c2pW[(size_t)k * 128 + n]);
    }
    // msg weights: 5 tiles, Klim=272
    for (int idx = gtid; idx < 5 * 128 * 64; idx += gstr) {
        const int s = idx & 63, n = (idx >> 6) & 127, t = idx >> 13;
        const int k = t * 64 + (((s >> 3) ^ (n & 7)) << 3) + (s & 7);
        wtm1[idx] = (k < 272) ? f2b(c1mW[(size_t)k * 128 + n]) : (ushort)0;
        wtm2[idx] = (k < 272) ? f2b(c2mW[(size_t)k * 128 + n]) : (ushort)0;
    }
}

__launch_bounds__(256)
__global__ void hist_kernel(const int* __restrict__ ei, int* __restrict__ counts, int E)
{
    const int e = blockIdx.x * 256 + threadIdx.x;
    if (e < E) atomicAdd(&counts[ei[E + e]], 1);
}

__launch_bounds__(256)
__global__ void scan_phase1(const int* __restrict__ counts, int* __restrict__ rowstart,
                            int* __restrict__ blocksums, int N)
{
    __shared__ int sdata[256];
    const int t = threadIdx.x;
    const int i = blockIdx.x * 256 + t;
    const int v = (i < N) ? counts[i] : 0;
    sdata[t] = v;
    __syncthreads();
    for (int off = 1; off < 256; off <<= 1) {
        const int add = (t >= off) ? sdata[t - off] : 0;
        __syncthreads();
        sdata[t] += add;
        __syncthreads();
    }
    if (i < N) rowstart[i] = sdata[t] - v;
    if (t == 255) blocksums[blockIdx.x] = sdata[255];
}

// merged scan phases 2+3: block vb sums blocksums[0..vb) itself (~196 blocks)
__launch_bounds__(256)
__global__ void scan_phase23(const int* __restrict__ counts, const int* __restrict__ bs,
                             int* __restrict__ rowstart, int* __restrict__ cursor,
                             float* __restrict__ degf, int N, int E)
{
    __shared__ int sdata[256];
    const int t = threadIdx.x;
    const int vb = blockIdx.x;
    int part = 0;
    for (int j = t; j < vb; j += 256) part += bs[j];
    sdata[t] = part;
    __syncthreads();
    for (int s = 128; s > 0; s >>= 1) {
        if (t < s) sdata[t] += sdata[t + s];
        __syncthreads();
    }
    const int off = sdata[0];
    const int i = vb * 256 + t;
    if (i < N) {
        const int rs = rowstart[i] + off;
        rowstart[i] = rs;
        cursor[i]   = rs;
        degf[i]     = (float)counts[i];
    }
    if (vb == 0 && t == 0) rowstart[N] = E;
}

__launch_bounds__(256)
__global__ void build_elist(const int* __restrict__ ei, int* __restrict__ cursor,
                            int2* __restrict__ elist, int E)
{
    const int e = blockIdx.x * 256 + threadIdx.x;
    if (e >= E) return;
    const int d = ei[E + e];
    const int pos = atomicAdd(&cursor[d], 1);
    elist[pos] = make_int2(ei[e], e);
}

// gather (R15 form): 16 lanes/node (4 nodes/wave), uint4/lane/edge, fully
// predicated batches of 8 (clamped src index, zeroed contribution). elist
// read once per 16-edge chunk + __shfl broadcast. ef fused (writes efp).
__launch_bounds__(256)
__global__ void gather(const int2* __restrict__ elist, const int* __restrict__ rowstart,
                       const ushort* __restrict__ h, ushort* __restrict__ agg,
                       const float* __restrict__ ef, ushort* __restrict__ aggef,
                       int N, int doEf)
{
    const int tid = threadIdx.x;
    const int grp = tid >> 4;          // 0..15 (node group within block)
    const int l   = tid & 15;          // lane within group
    const int nvb = (N + 15) / 16;     // 16 nodes per block
    for (int vb = blockIdx.x; vb < nvb; vb += gridDim.x) {
        const int node = vb * 16 + grp;
        if (node >= N) continue;
        const int beg = rowstart[node];
        const int end = rowstart[node + 1];
        float a0 = 0.f, a1 = 0.f, a2 = 0.f, a3 = 0.f;
        float a4 = 0.f, a5 = 0.f, a6 = 0.f, a7 = 0.f;
        float efacc = 0.f;
        for (int k = beg; k < end; k += 16) {
            const int cnt = min(16, end - k);
            const int2 ep = elist[k + min(l, cnt - 1)];   // 16 records, 1 vec load
            for (int j = 0; j < cnt; j += 8) {
                uint4 v[8];
                float efv[8];
#pragma unroll
                for (int jj = 0; jj < 8; ++jj) {
                    const int idx = min(j + jj, cnt - 1);
                    const int s = __shfl(ep.x, idx, 16);
                    v[jj] = *(const uint4*)&h[((size_t)s << 7) + (l << 3)];
                    if (doEf) {
                        const int y = __shfl(ep.y, idx, 16);
                        efv[jj] = ef[((size_t)y << 4) + l];
                    }
                }
#pragma unroll
                for (int jj = 0; jj < 8; ++jj) {
                    if (j + jj >= cnt) {
                        v[jj] = make_uint4(0, 0, 0, 0);
                        efv[jj] = 0.f;
                    }
                    a0 += b2f((ushort)(v[jj].x & 0xffff));
                    a1 += b2f((ushort)(v[jj].x >> 16));
                    a2 += b2f((ushort)(v[jj].y & 0xffff));
                    a3 += b2f((ushort)(v[jj].y >> 16));
                    a4 += b2f((ushort)(v[jj].z & 0xffff));
                    a5 += b2f((ushort)(v[jj].z >> 16));
                    a6 += b2f((ushort)(v[jj].w & 0xffff));
                    a7 += b2f((ushort)(v[jj].w >> 16));
                    if (doEf) efacc += efv[jj];
                }
            }
        }
        uint4 o;
        o.x = pack2(a0, a1);
        o.y = pack2(a2, a3);
        o.z = pack2(a4, a5);
        o.w = pack2(a6, a7);
        *(uint4*)&agg[((size_t)node << 7) + (l << 3)] = o;
        if (doEf) aggef[((size_t)node << 6) + l] = f2b(efacc);
    }
}

// head: out[q] = z[a].topdot + z[b].botdot + lpb  (z = {za0,za1,zb0,zb1})
__launch_bounds__(256)
__global__ void head_kernel(const float4* __restrict__ z, const int* __restrict__ eli,
                            const float* __restrict__ lpb, float* __restrict__ out, int Q)
{
    const int q = blockIdx.x * 256 + threadIdx.x;
    if (q >= Q) return;
    const int a = eli[q];
    const int b = eli[Q + q];
    const float4 za = z[a];
    const float4 zb = z[b];
    float2 o = make_float2(za.x + zb.z + lpb[0], za.y + zb.w + lpb[1]);
    *(float2*)&out[(size_t)q * 2] = o;
}

extern "C" void kernel_launch(void* const* d_in, const int* in_sizes, int n_in,
                              void* d_out, int out_size, void* d_ws, size_t ws_size,
                              hipStream_t stream)
{
    const float* nf   = (const float*)d_in[0];
    const int*   ei   = (const int*)d_in[1];
    const float* ef   = (const float*)d_in[2];
    const int*   eli  = (const int*)d_in[3];
    const float* c1pW = (const float*)d_in[4];
    const float* c1pb = (const float*)d_in[5];
    const float* c1mW = (const float*)d_in[6];
    const float* c1mb = (const float*)d_in[7];
    const float* c2pW = (const float*)d_in[8];
    const float* c2pb = (const float*)d_in[9];
    const float* c2mW = (const float*)d_in[10];
    const float* c2mb = (const float*)d_in[11];
    const float* lpW  = (const float*)d_in[12];
    const float* lpb  = (const float*)d_in[13];
    float* out = (float*)d_out;

    const int N = in_sizes[0] / 128;
    const int E = in_sizes[1] / 2;
    const int Q = in_sizes[3] / 2;

    // ---- workspace layout ----
    float* DEG = (float*)d_ws;                 // N
    float* z   = DEG + N;                      // N*4 fp32 (head projections)
    int* counts    = (int*)(z + (size_t)N * 4);// N
    int* rowstart  = counts + N;               // N+1
    int* cursor    = rowstart + N + 1;         // N
    int* blocksums = cursor + N;               // 1024 pad
    uintptr_t ep8 = (uintptr_t)(blocksums + 1024);
    ep8 = (ep8 + 7) & ~(uintptr_t)7;
    int2* elist = (int2*)ep8;                  // E int2 (src, edge id)
    uintptr_t up = (uintptr_t)(elist + E);
    up = (up + 15) & ~(uintptr_t)15;
    ushort* nf_bf  = (ushort*)up;              // N*128
    ushort* h_bf   = nf_bf  + (size_t)N * 128; // N*128
    ushort* agg_bf = h_bf   + (size_t)N * 128; // N*128
    ushort* efp    = agg_bf + (size_t)N * 128; // N*64 (zero-padded ef sums)
    ushort* wtp1   = efp    + (size_t)N * 64;  // 2*128*64
    ushort* wtm1   = wtp1 + 2 * 128 * 64;      // 5*128*64
    ushort* wtp2   = wtm1 + 5 * 128 * 64;      // 2*128*64
    ushort* wtm2   = wtp2 + 2 * 128 * 64;      // 5*128*64

    const int gemmGrid = (N + 63) / 64;
    const int eGrid    = (E + 255) / 256;
    const int nGrid    = (N + 255) / 256;
    const int gGrid    = (N + 15) / 16;
    const int headGrid = (Q + 255) / 256;

    // ---- prep + CSR build ----
    prep<<<nGrid, 256, 0, stream>>>(nf, nf_bf, c1pW, c2pW, c1mW, c2mW,
                                    wtp1, wtp2, wtm1, wtm2, efp, counts, N);
    hist_kernel<<<eGrid, 256, 0, stream>>>(ei, counts, E);
    scan_phase1<<<nGrid, 256, 0, stream>>>(counts, rowstart, blocksums, N);
    scan_phase23<<<nGrid, 256, 0, stream>>>(counts, blocksums, rowstart, cursor, DEG, N, E);
    build_elist<<<eGrid, 256, 0, stream>>>(ei, cursor, elist, E);

    // ---- conv1 ----
    gemm_mfma<<<gemmGrid, 256, 0, stream>>>(nf_bf, nullptr, nullptr, DEG, wtp1,
                                            c1pb, h_bf, nullptr, nullptr, N, 128,
                                            F_RELU | F_OUTB);
    gather<<<gGrid, 256, 0, stream>>>(elist, rowstart, h_bf, agg_bf, ef, efp, N, 1);

    // ---- conv1-msg + conv2-pre (fused, dual-acc, h updated in place) ----
    gemm_msg_pre<<<gemmGrid, 256, 0, stream>>>(h_bf, agg_bf, efp, DEG, wtm1, c1mb,
                                               wtp2, c2pb, h_bf, N);

    // ---- conv2 ----
    gather<<<gGrid, 256, 0, stream>>>(elist, rowstart, h_bf, agg_bf, nullptr, nullptr, N, 0);
    gemm_mfma<<<gemmGrid, 256, 0, stream>>>(h_bf, agg_bf, efp, DEG, wtm2,
                                            c2mb, nullptr, lpW, z, N, 320,
                                            F_MSG | F_HEAD);

    // ---- head ----
    head_kernel<<<headGrid, 256, 0, stream>>>((const float4*)z, eli, lpb, out, Q);
}